// Round 1
// baseline (76.323 us; speedup 1.0000x reference)
//
#include <hip/hip_runtime.h>

// Problem constants (from reference)
#define BB     4
#define C_ADD  4
#define HH_    496
#define WW_    432
#define NB_    50
#define SCALE_ 0.8f

// One block (= one wave of 64) per (b, nb) box. Each box only overlaps a
// small window of the 496x432 grid (dx,dy <= 8 -> <= ~16x16 cells at 0.8
// spacing), so we compute channel-sum occupancy ON THE FLY for window cells
// only, instead of a full-pass occupancy kernel over 28 MB of input.
__global__ __launch_bounds__(64)
void points_iou_kernel(const float* __restrict__ added,   // [B,4,H,W]
                       const float* __restrict__ orig,    // [B,5,H,W]
                       const float* __restrict__ boxes,   // [B,NB,7]
                       float* __restrict__ out)           // [1]
{
    const int HW = HH_ * WW_;
    const int blk = blockIdx.x;            // b*NB + nb
    const int b   = blk / NB_;

    const float* bx = boxes + (size_t)blk * 7;
    const float cx = bx[0], cy = bx[1], cz = bx[2];
    const float dx = bx[3], dy = bx[4], dz = bx[5];
    const float hd = bx[6];
    const float c = cosf(hd), s = sinf(hd);

    // z-check: pz = 0 - cz
    const bool inz = fabsf(-cz) <= dz * 0.5f;

    // Rotated box AABB extent in world coords
    const float ex = 0.5f * (dx * fabsf(c) + dy * fabsf(s));
    const float ey = 0.5f * (dx * fabsf(s) + dy * fabsf(c));

    // Grid-cell window, expanded by 1 cell to absorb float rounding
    int hmin = max(0,       (int)ceilf ((cx - ex) / SCALE_) - 1);
    int hmax = min(HH_ - 1, (int)floorf((cx + ex) / SCALE_) + 1);
    int wmin = max(0,       (int)ceilf ((cy - ey) / SCALE_) - 1);
    int wmax = min(WW_ - 1, (int)floorf((cy + ey) / SCALE_) + 1);
    const int nh = hmax - hmin + 1;
    const int nw = wmax - wmin + 1;

    int inter = 0, uni = 0;

    if (inz && nh > 0 && nw > 0) {
        const int ncell = nh * nw;
        const float* ab = added + (size_t)b * 4 * HW;        // channels 0..3
        const float* ob = orig  + (size_t)b * 5 * HW + HW;   // channels 1..4

        for (int idx = threadIdx.x; idx < ncell; idx += 64) {
            const int h = hmin + idx / nw;
            const int w = wmin + idx % nw;
            const float px = (float)h * SCALE_ - cx;
            const float py = (float)w * SCALE_ - cy;
            const float lx =  px * c + py * s;
            const float ly = -px * s + py * c;
            if (fabsf(lx) <= dx * 0.5f && fabsf(ly) <= dy * 0.5f) {
                const int p = h * WW_ + w;
                const float ps = ab[p] + ab[p + HW] + ab[p + 2 * HW] + ab[p + 3 * HW];
                const float os = ob[p] + ob[p + HW] + ob[p + 2 * HW] + ob[p + 3 * HW];
                const bool op = (ps != 0.0f);
                const bool oo = (os != 0.0f);
                inter += (op && oo) ? 1 : 0;
                uni   += (op || oo) ? 1 : 0;
            }
        }
    }

    // Wave-level reduction (block == 1 wave == 64 lanes)
    #pragma unroll
    for (int off = 32; off > 0; off >>= 1) {
        inter += __shfl_down(inter, off);
        uni   += __shfl_down(uni,   off);
    }

    if (threadIdx.x == 0 && uni > 0) {
        // iou = inter/max(union,1); union>0 integer -> inter/union. /B fold.
        atomicAdd(out, 0.25f * (float)inter / (float)uni);
    }
}

extern "C" void kernel_launch(void* const* d_in, const int* in_sizes, int n_in,
                              void* d_out, int out_size, void* d_ws, size_t ws_size,
                              hipStream_t stream) {
    const float* added = (const float*)d_in[0];
    const float* orig  = (const float*)d_in[1];
    const float* boxes = (const float*)d_in[2];
    float* out = (float*)d_out;

    // d_out is poisoned to 0xAA before every launch; zero it for atomicAdd.
    hipMemsetAsync(out, 0, sizeof(float), stream);

    points_iou_kernel<<<BB * NB_, 64, 0, stream>>>(added, orig, boxes, out);
}

// Round 2
// 75.404 us; speedup vs baseline: 1.0122x; 1.0122x over previous
//
#include <hip/hip_runtime.h>

// Problem constants (from reference)
#define BB     4
#define C_ADD  4
#define HH_    496
#define WW_    432
#define NB_    50
#define SCALE_ 0.8f

// Phase 1: one block (256 threads = 4 waves) per (b, nb) box. Each box
// overlaps only a small window of the 496x432 grid (dx,dy <= 8 -> <= ~23x23
// cells at 0.8 spacing), so channel-sum occupancy is computed on the fly for
// window cells only (~1-3 loop iterations per lane at 256 threads; 800 waves
// total -> ~3 waves/CU for HBM latency hiding). Per-box IoU contribution is
// written to ws[blk]; no atomics, no pre-zeroed output needed.
__global__ __launch_bounds__(256)
void box_iou_kernel(const float* __restrict__ added,   // [B,4,H,W]
                    const float* __restrict__ orig,    // [B,5,H,W]
                    const float* __restrict__ boxes,   // [B,NB,7]
                    float* __restrict__ ws)            // [B*NB] per-box iou
{
    __shared__ int s_inter[4];
    __shared__ int s_uni[4];

    const int HW  = HH_ * WW_;
    const int blk = blockIdx.x;            // b*NB + nb
    const int b   = blk / NB_;

    const float* bx = boxes + (size_t)blk * 7;
    const float cx = bx[0], cy = bx[1], cz = bx[2];
    const float dx = bx[3], dy = bx[4], dz = bx[5];
    const float hd = bx[6];
    const float c = cosf(hd), s = sinf(hd);

    // z-check: pz = 0 - cz
    const bool inz = fabsf(-cz) <= dz * 0.5f;

    // Rotated box AABB extent in world coords
    const float ex = 0.5f * (dx * fabsf(c) + dy * fabsf(s));
    const float ey = 0.5f * (dx * fabsf(s) + dy * fabsf(c));

    // Grid-cell window, expanded by 1 cell to absorb float rounding
    const int hmin = max(0,       (int)ceilf ((cx - ex) / SCALE_) - 1);
    const int hmax = min(HH_ - 1, (int)floorf((cx + ex) / SCALE_) + 1);
    const int wmin = max(0,       (int)ceilf ((cy - ey) / SCALE_) - 1);
    const int wmax = min(WW_ - 1, (int)floorf((cy + ey) / SCALE_) + 1);
    const int nh = hmax - hmin + 1;
    const int nw = wmax - wmin + 1;

    int inter = 0, uni = 0;

    if (inz && nh > 0 && nw > 0) {
        const int ncell = nh * nw;
        const float* ab = added + (size_t)b * 4 * HW;        // channels 0..3
        const float* ob = orig  + (size_t)b * 5 * HW + HW;   // channels 1..4

        for (int idx = threadIdx.x; idx < ncell; idx += 256) {
            const int h = hmin + idx / nw;
            const int w = wmin + idx % nw;
            const float px = (float)h * SCALE_ - cx;
            const float py = (float)w * SCALE_ - cy;
            const float lx =  px * c + py * s;
            const float ly = -px * s + py * c;
            if (fabsf(lx) <= dx * 0.5f && fabsf(ly) <= dy * 0.5f) {
                const int p = h * WW_ + w;
                const float ps = ab[p] + ab[p + HW] + ab[p + 2 * HW] + ab[p + 3 * HW];
                const float os = ob[p] + ob[p + HW] + ob[p + 2 * HW] + ob[p + 3 * HW];
                const bool op = (ps != 0.0f);
                const bool oo = (os != 0.0f);
                inter += (op && oo) ? 1 : 0;
                uni   += (op || oo) ? 1 : 0;
            }
        }
    }

    // Wave-level reduction (64 lanes)
    #pragma unroll
    for (int off = 32; off > 0; off >>= 1) {
        inter += __shfl_down(inter, off);
        uni   += __shfl_down(uni,   off);
    }

    const int wid = threadIdx.x >> 6;
    if ((threadIdx.x & 63) == 0) { s_inter[wid] = inter; s_uni[wid] = uni; }
    __syncthreads();

    if (threadIdx.x == 0) {
        const int I = s_inter[0] + s_inter[1] + s_inter[2] + s_inter[3];
        const int U = s_uni[0]   + s_uni[1]   + s_uni[2]   + s_uni[3];
        // iou = inter/max(union,1); integer union>0 -> inter/union. /B fold.
        ws[blk] = (U > 0) ? 0.25f * (float)I / (float)U : 0.0f;
    }
}

// Phase 2: single wave sums the 200 per-box contributions into d_out.
// Runs after phase 1 on the same stream; kernel-boundary ordering guarantees
// visibility of ws writes across XCDs.
__global__ __launch_bounds__(64)
void reduce_kernel(const float* __restrict__ ws, float* __restrict__ out)
{
    float v = 0.0f;
    for (int i = threadIdx.x; i < BB * NB_; i += 64) v += ws[i];
    #pragma unroll
    for (int off = 32; off > 0; off >>= 1) v += __shfl_down(v, off);
    if (threadIdx.x == 0) out[0] = v;
}

extern "C" void kernel_launch(void* const* d_in, const int* in_sizes, int n_in,
                              void* d_out, int out_size, void* d_ws, size_t ws_size,
                              hipStream_t stream) {
    const float* added = (const float*)d_in[0];
    const float* orig  = (const float*)d_in[1];
    const float* boxes = (const float*)d_in[2];
    float* out = (float*)d_out;
    float* ws  = (float*)d_ws;   // first B*NB floats used for per-box iou

    box_iou_kernel<<<BB * NB_, 256, 0, stream>>>(added, orig, boxes, ws);
    reduce_kernel<<<1, 64, 0, stream>>>(ws, out);
}